// Round 1
// baseline (1137.296 us; speedup 1.0000x reference)
//
#include <hip/hip_runtime.h>
#include <math.h>

// Problem constants
#define Bb 64
#define Tt 2048
#define Jj 128
#define Dd 200
#define GD 800           // G feature dim = 4*Dd
#define PAD 204          // padded LDS row stride (floats); 204*4=816 B, 16B aligned
#define TILE 32          // H rows per block
#define RT 4             // rows per wave
#define NTH 512          // threads per block (8 waves)

// ---------------------------------------------------------------------------
// K1: fused S = wh.H + wu.U + (H*wm).U^T + b ; row softmax over j ;
//     U_tilde = P.U ; writes G[:,0:600] and m[b,t] = max_j S
// ---------------------------------------------------------------------------
__global__ __launch_bounds__(NTH) void k_main(
    const float* __restrict__ H, const float* __restrict__ U,
    const float* __restrict__ w, const float* __restrict__ bptr,
    float* __restrict__ G, float* __restrict__ mrow)
{
    __shared__ float Ush[Jj][PAD];    // raw U_b
    __shared__ float Hsh[TILE][PAD];  // raw H tile
    __shared__ float wmsh[PAD];
    __shared__ float su[Jj];          // dot(U_j, wu) + b

    const int tid  = threadIdx.x;
    const int lane = tid & 63;
    const int wv   = tid >> 6;
    const int b    = blockIdx.y;
    const int t0   = blockIdx.x * TILE;

    const float bb = bptr[0];
    // preload wh / wu fragments (d = lane, lane+64, lane+128, lane+192)
    const float wh0 = w[lane], wh1 = w[64 + lane], wh2 = w[128 + lane];
    const float wh3 = (lane < 8) ? w[192 + lane] : 0.f;
    const float wu0 = w[200 + lane], wu1 = w[264 + lane], wu2 = w[328 + lane];
    const float wu3 = (lane < 8) ? w[392 + lane] : 0.f;

    // ---- stage U_b (128 x 200 f32) ----
    const float* Ub = U + (size_t)b * Jj * Dd;
    for (int i = tid; i < Jj * 50; i += NTH) {
        int row = i / 50, c = i % 50;
        float4 v = *(const float4*)(Ub + row * Dd + c * 4);
        *(float4*)&Ush[row][c * 4] = v;
    }
    // ---- stage H tile (32 x 200 f32) ----
    const float* Hb = H + ((size_t)b * Tt + t0) * Dd;
    for (int i = tid; i < TILE * 50; i += NTH) {
        int row = i / 50, c = i % 50;
        float4 v = *(const float4*)(Hb + row * Dd + c * 4);
        *(float4*)&Hsh[row][c * 4] = v;
    }
    // ---- stage wm ----
    for (int i = tid; i < PAD; i += NTH) wmsh[i] = (i < Dd) ? w[400 + i] : 0.f;
    __syncthreads();

    // ---- su[j] = dot(U_j, wu) + b : wave wv handles j = wv*16 .. wv*16+15 ----
    for (int k = 0; k < 16; ++k) {
        int j = wv * 16 + k;
        float v = Ush[j][lane] * wu0 + Ush[j][64 + lane] * wu1 + Ush[j][128 + lane] * wu2;
        if (lane < 8) v += Ush[j][192 + lane] * wu3;
        #pragma unroll
        for (int off = 32; off; off >>= 1) v += __shfl_xor(v, off);
        if (lane == 0) su[j] = v + bb;
    }
    // ---- sh[r] = dot(H_row, wh) for this wave's rows ----
    const int r0 = wv * RT;
    float shreg[RT];
    #pragma unroll
    for (int r = 0; r < RT; ++r) {
        int row = r0 + r;
        float v = Hsh[row][lane] * wh0 + Hsh[row][64 + lane] * wh1 + Hsh[row][128 + lane] * wh2;
        if (lane < 8) v += Hsh[row][192 + lane] * wh3;
        #pragma unroll
        for (int off = 32; off; off >>= 1) v = v + __shfl_xor(v, off);
        shreg[r] = v;
    }
    __syncthreads();

    // ---- S pass: lane covers j = lane and j = lane+64 ----
    float acc0[RT] = {0.f, 0.f, 0.f, 0.f};
    float acc1[RT] = {0.f, 0.f, 0.f, 0.f};
    #pragma unroll 2
    for (int c = 0; c < 50; ++c) {
        float4 wm4 = *(const float4*)&wmsh[c * 4];
        float4 u0  = *(const float4*)&Ush[lane][c * 4];
        float4 u1  = *(const float4*)&Ush[64 + lane][c * 4];
        #pragma unroll
        for (int r = 0; r < RT; ++r) {
            float4 h4 = *(const float4*)&Hsh[r0 + r][c * 4];
            float hmx = h4.x * wm4.x, hmy = h4.y * wm4.y;
            float hmz = h4.z * wm4.z, hmw = h4.w * wm4.w;
            acc0[r] += hmx * u0.x + hmy * u0.y + hmz * u0.z + hmw * u0.w;
            acc1[r] += hmx * u1.x + hmy * u1.y + hmz * u1.z + hmw * u1.w;
        }
    }

    // ---- softmax over j (128 values: 2 per lane) ----
    const float su0 = su[lane], su1 = su[64 + lane];
    float p0[RT], p1[RT];
    #pragma unroll
    for (int r = 0; r < RT; ++r) {
        float s0 = acc0[r] + shreg[r] + su0;
        float s1 = acc1[r] + shreg[r] + su1;
        float mx = fmaxf(s0, s1);
        #pragma unroll
        for (int off = 32; off; off >>= 1) mx = fmaxf(mx, __shfl_xor(mx, off));
        float e0 = __expf(s0 - mx), e1 = __expf(s1 - mx);
        float sm = e0 + e1;
        #pragma unroll
        for (int off = 32; off; off >>= 1) sm += __shfl_xor(sm, off);
        float inv = 1.f / sm;
        p0[r] = e0 * inv;
        p1[r] = e1 * inv;
        if (lane == 0) mrow[(size_t)b * Tt + t0 + r0 + r] = mx;
    }

    // ---- U_tilde pass: lanes over d (lane < 50 covers d = 4*lane .. 4*lane+3) ----
    const int dchunk = (lane < 50) ? lane : 49;
    float utx[RT] = {0, 0, 0, 0}, uty[RT] = {0, 0, 0, 0};
    float utz[RT] = {0, 0, 0, 0}, utw[RT] = {0, 0, 0, 0};
    for (int j = 0; j < 64; ++j) {
        float4 uv = *(const float4*)&Ush[j][dchunk * 4];
        #pragma unroll
        for (int r = 0; r < RT; ++r) {
            float pv = __shfl(p0[r], j);
            utx[r] += pv * uv.x; uty[r] += pv * uv.y;
            utz[r] += pv * uv.z; utw[r] += pv * uv.w;
        }
    }
    for (int j = 0; j < 64; ++j) {
        float4 uv = *(const float4*)&Ush[64 + j][dchunk * 4];
        #pragma unroll
        for (int r = 0; r < RT; ++r) {
            float pv = __shfl(p1[r], j);
            utx[r] += pv * uv.x; uty[r] += pv * uv.y;
            utz[r] += pv * uv.z; utw[r] += pv * uv.w;
        }
    }

    // ---- epilogue: G[:,0:200]=H, [200:400]=U_tilde, [400:600]=H*U_tilde ----
    if (lane < 50) {
        #pragma unroll
        for (int r = 0; r < RT; ++r) {
            int t = t0 + r0 + r;
            float* grow = G + ((size_t)b * Tt + t) * GD;
            float4 h4 = *(const float4*)&Hsh[r0 + r][lane * 4];
            float4 ut; ut.x = utx[r]; ut.y = uty[r]; ut.z = utz[r]; ut.w = utw[r];
            float4 hu; hu.x = h4.x * ut.x; hu.y = h4.y * ut.y;
            hu.z = h4.z * ut.z; hu.w = h4.w * ut.w;
            *(float4*)(grow + lane * 4)       = h4;
            *(float4*)(grow + 200 + lane * 4) = ut;
            *(float4*)(grow + 400 + lane * 4) = hu;
        }
    }
}

// ---------------------------------------------------------------------------
// K2a: q[b,:] = softmax over t of m[b,:]  (also output 1)
// ---------------------------------------------------------------------------
__global__ __launch_bounds__(256) void k_q(
    const float* __restrict__ mrow, float* __restrict__ q)
{
    __shared__ float red[4];
    __shared__ float sM, sS;
    const int b = blockIdx.x, tid = threadIdx.x;
    const int lane = tid & 63, wv = tid >> 6;
    const float* mb = mrow + (size_t)b * Tt;

    float lm = -1e30f;
    for (int i = tid; i < Tt; i += 256) lm = fmaxf(lm, mb[i]);
    #pragma unroll
    for (int off = 32; off; off >>= 1) lm = fmaxf(lm, __shfl_xor(lm, off));
    if (lane == 0) red[wv] = lm;
    __syncthreads();
    if (tid == 0) sM = fmaxf(fmaxf(red[0], red[1]), fmaxf(red[2], red[3]));
    __syncthreads();
    const float M = sM;

    float ls = 0.f;
    for (int i = tid; i < Tt; i += 256) ls += __expf(mb[i] - M);
    #pragma unroll
    for (int off = 32; off; off >>= 1) ls += __shfl_xor(ls, off);
    __syncthreads();
    if (lane == 0) red[wv] = ls;
    __syncthreads();
    if (tid == 0) sS = red[0] + red[1] + red[2] + red[3];
    __syncthreads();
    const float invS = 1.f / sS;

    for (int i = tid; i < Tt; i += 256)
        q[(size_t)b * Tt + i] = __expf(mb[i] - M) * invS;
}

// ---------------------------------------------------------------------------
// K2b: htil[b,d] = sum_t q[b,t] * H[b,t,d]   (atomic partial sums)
// ---------------------------------------------------------------------------
__global__ __launch_bounds__(256) void k_ht(
    const float* __restrict__ H, const float* __restrict__ q,
    float* __restrict__ htil)
{
    const int b = blockIdx.y, ch = blockIdx.x;
    const int d = threadIdx.x;
    const float* Hb = H + (size_t)b * Tt * Dd;
    const float* qb = q + (size_t)b * Tt;
    if (d < Dd) {
        float acc = 0.f;
        const int ts = ch * 128;
        for (int t = ts; t < ts + 128; ++t)
            acc += qb[t] * Hb[(size_t)t * Dd + d];
        atomicAdd(&htil[b * Dd + d], acc);
    }
}

// ---------------------------------------------------------------------------
// K3: G[:,600:800] = H * htil[b,:]
// ---------------------------------------------------------------------------
__global__ __launch_bounds__(256) void k_g3(
    const float* __restrict__ H, const float* __restrict__ htil,
    float* __restrict__ G)
{
    const int idx = blockIdx.x * 256 + threadIdx.x;
    if (idx >= Bb * Tt * Dd) return;
    const int d  = idx % Dd;
    const int bt = idx / Dd;
    const int b  = bt >> 11;
    G[(size_t)bt * GD + 600 + d] = H[idx] * htil[b * Dd + d];
}

// ---------------------------------------------------------------------------
extern "C" void kernel_launch(void* const* d_in, const int* in_sizes, int n_in,
                              void* d_out, int out_size, void* d_ws, size_t ws_size,
                              hipStream_t stream)
{
    const float* H    = (const float*)d_in[0];
    const float* U    = (const float*)d_in[1];
    const float* w    = (const float*)d_in[2];
    const float* bptr = (const float*)d_in[3];

    float* G    = (float*)d_out;
    float* q    = G + (size_t)Bb * Tt * GD;     // output 1 region
    float* mrow = (float*)d_ws;                 // B*T floats
    float* htil = mrow + (size_t)Bb * Tt;       // B*Dd floats

    hipMemsetAsync(htil, 0, (size_t)Bb * Dd * sizeof(float), stream);

    dim3 g1(Tt / TILE, Bb);
    k_main<<<g1, NTH, 0, stream>>>(H, U, w, bptr, G, mrow);

    k_q<<<Bb, 256, 0, stream>>>(mrow, q);

    dim3 g2(Tt / 128, Bb);
    k_ht<<<g2, 256, 0, stream>>>(H, q, htil);

    const int n3 = Bb * Tt * Dd;
    k_g3<<<(n3 + 255) / 256, 256, 0, stream>>>(H, htil, G);
}

// Round 3
// 712.282 us; speedup vs baseline: 1.5967x; 1.5967x over previous
//
#include <hip/hip_runtime.h>
#include <math.h>

typedef __attribute__((ext_vector_type(8))) short bf16x8;
typedef __attribute__((ext_vector_type(4))) float f32x4;

#define Bb 64
#define Tt 2048
#define Jj 128
#define Dd 200
#define GD 800
#define TILE 64
#define NTH 1024

// LDS byte offsets (all 256-aligned so the XOR-bit-4 swizzle stays in-region)
#define OFF_USH 0u        // [128][224] bf16, stride 448 B  (U, k-contiguous)
#define OFF_UJT 57344u    // [208][128] bf16, stride 256 B  (U^T, j-contiguous); later overlaid by UTSH f32 [64][204] stride 816 B
#define OFF_HMS 110592u   // [64][224] bf16, stride 448 B   (H * wm)
#define OFF_PSH 139264u   // [64][128] bf16, stride 256 B   (P)
#define OFF_SUS 155648u   // [128] f32   su[j] = wu.U_j + b
#define OFF_SHS 156160u   // [64]  f32   sh[t] = wh.H_t
#define OFF_SMX 156416u   // [64][4] f32 per-cg partial row max
#define OFF_SSM 157440u   // [64][4] f32 per-cg partial row sum
#define SMEM_BYTES 158464u

__device__ __forceinline__ unsigned short f2bf(float f) {
    union { float f; unsigned u; } v; v.f = f;
    unsigned r = v.u + 0x7FFFu + ((v.u >> 16) & 1u);
    return (unsigned short)(r >> 16);
}

__device__ __forceinline__ bf16x8 pack8(f32x4 a, f32x4 b) {
    bf16x8 o;
    o[0] = (short)f2bf(a[0]); o[1] = (short)f2bf(a[1]);
    o[2] = (short)f2bf(a[2]); o[3] = (short)f2bf(a[3]);
    o[4] = (short)f2bf(b[0]); o[5] = (short)f2bf(b[1]);
    o[6] = (short)f2bf(b[2]); o[7] = (short)f2bf(b[3]);
    return o;
}

// ---------------------------------------------------------------------------
// K1: fully fused S -> softmax -> U_tilde via MFMA; writes G[:,0:600], mrow
// ---------------------------------------------------------------------------
__global__ __launch_bounds__(NTH) void k_main(
    const float* __restrict__ H, const float* __restrict__ U,
    const float* __restrict__ wt, const float* __restrict__ bptr,
    float* __restrict__ G, float* __restrict__ mrow)
{
    __shared__ __align__(16) char smem[SMEM_BYTES];

    const int tid  = threadIdx.x;
    const int lane = tid & 63;
    const int wv   = tid >> 6;          // wave 0..15

    // XCD-contiguous block swizzle (2048 = 8 * 256, bijective)
    const int lin = blockIdx.x;
    const int wg  = (lin & 7) * 256 + (lin >> 3);
    const int b   = wg >> 5;
    const int t0  = (wg & 31) * TILE;

    const float* Hb = H + ((size_t)b * Tt + t0) * Dd;
    const float* Ub = U + (size_t)b * Jj * Dd;
    const float  bb = bptr[0];

    const float wh0 = wt[lane], wh1 = wt[64 + lane], wh2 = wt[128 + lane];
    const float wh3 = (lane < 8) ? wt[192 + lane] : 0.f;
    const float wu0 = wt[200 + lane], wu1 = wt[264 + lane], wu2 = wt[328 + lane];
    const float wu3 = (lane < 8) ? wt[392 + lane] : 0.f;

    // ---- stage U -> Ush bf16 [128][224] (k-pad with zeros), swizzled ----
    for (int i = tid; i < 128 * 28; i += NTH) {
        int row = i / 28, c8 = i % 28;
        bf16x8 val = {0,0,0,0,0,0,0,0};
        if (c8 < 25) {
            const float* p = Ub + row * Dd + c8 * 8;
            val = pack8(*(const f32x4*)p, *(const f32x4*)(p + 4));
        }
        unsigned a = OFF_USH + (unsigned)row * 448u + (unsigned)c8 * 16u;
        *(bf16x8*)(smem + (a ^ ((unsigned)(row & 7) << 4))) = val;
    }
    // ---- stage H*wm -> Hms bf16 [64][224], swizzled ----
    for (int i = tid; i < TILE * 28; i += NTH) {
        int row = i / 28, c8 = i % 28;
        bf16x8 val = {0,0,0,0,0,0,0,0};
        if (c8 < 25) {
            const float* p  = Hb + row * Dd + c8 * 8;
            const float* wp = wt + 400 + c8 * 8;
            f32x4 h0 = *(const f32x4*)p,        h1 = *(const f32x4*)(p + 4);
            f32x4 w0 = *(const f32x4*)wp,       w1 = *(const f32x4*)(wp + 4);
            val = pack8(h0 * w0, h1 * w1);
        }
        unsigned a = OFF_HMS + (unsigned)row * 448u + (unsigned)c8 * 16u;
        *(bf16x8*)(smem + (a ^ ((unsigned)(row & 7) << 4))) = val;
    }
    // ---- su[j] (f32, from global) : wave wv -> j = wv*8..wv*8+7 ----
    for (int jj = 0; jj < 8; ++jj) {
        int j = wv * 8 + jj;
        const float* up = Ub + j * Dd;
        float v = up[lane] * wu0 + up[64 + lane] * wu1 + up[128 + lane] * wu2;
        if (lane < 8) v += up[192 + lane] * wu3;
        #pragma unroll
        for (int off = 32; off; off >>= 1) v += __shfl_xor(v, off);
        if (lane == 0) *(float*)(smem + OFF_SUS + (unsigned)j * 4u) = v + bb;
    }
    // ---- sh[t] (f32, from global) : wave wv -> rows wv*4..wv*4+3 ----
    for (int rr = 0; rr < 4; ++rr) {
        int row = wv * 4 + rr;
        const float* hp = Hb + row * Dd;
        float v = hp[lane] * wh0 + hp[64 + lane] * wh1 + hp[128 + lane] * wh2;
        if (lane < 8) v += hp[192 + lane] * wh3;
        #pragma unroll
        for (int off = 32; off; off >>= 1) v += __shfl_xor(v, off);
        if (lane == 0) *(float*)(smem + OFF_SHS + (unsigned)row * 4u) = v;
    }
    __syncthreads();   // sync1: Ush/Hms ready

    // ---- build Ujt[d][j] = Ush[j][d] (bf16, swizzled), zeros for d>=200 ----
    for (int i = tid; i < 208 * 64; i += NTH) {
        int d  = i >> 6;
        int jp = (i & 63) << 1;
        unsigned short v0 = 0, v1 = 0;
        if (d < Dd) {
            unsigned a0 = OFF_USH + (unsigned)jp * 448u + ((unsigned)d << 1);
            v0 = *(const unsigned short*)(smem + (a0 ^ ((unsigned)(jp & 7) << 4)));
            unsigned a1 = OFF_USH + (unsigned)(jp + 1) * 448u + ((unsigned)d << 1);
            v1 = *(const unsigned short*)(smem + (a1 ^ ((unsigned)((jp + 1) & 7) << 4)));
        }
        unsigned pk = (unsigned)v0 | ((unsigned)v1 << 16);
        unsigned wa = OFF_UJT + (unsigned)d * 256u + (unsigned)((i & 63) << 2);
        *(unsigned*)(smem + (wa ^ ((unsigned)(d & 7) << 4))) = pk;
    }

    // ---- S phase: wave (rg,cgS) owns rows rg*16+.., cols cgS*32 (2 tiles) ----
    const int rg = wv >> 2, cgS = wv & 3;
    const int rowA = rg * 16 + (lane & 15);
    const unsigned kfo = (unsigned)(((lane >> 4) << 4));
    f32x4 accS0 = {0.f, 0.f, 0.f, 0.f}, accS1 = {0.f, 0.f, 0.f, 0.f};
    #pragma unroll
    for (int ki = 0; ki < 7; ++ki) {
        unsigned ab = OFF_HMS + (unsigned)rowA * 448u + (unsigned)ki * 64u + kfo;
        bf16x8 af = *(const bf16x8*)(smem + (ab ^ ((unsigned)(rowA & 7) << 4)));
        int j0 = cgS * 32 + (lane & 15);
        unsigned b0 = OFF_USH + (unsigned)j0 * 448u + (unsigned)ki * 64u + kfo;
        bf16x8 bf0 = *(const bf16x8*)(smem + (b0 ^ ((unsigned)(j0 & 7) << 4)));
        accS0 = __builtin_amdgcn_mfma_f32_16x16x32_bf16(af, bf0, accS0, 0, 0, 0);
        int j1 = j0 + 16;
        unsigned b1 = OFF_USH + (unsigned)j1 * 448u + (unsigned)ki * 64u + kfo;
        bf16x8 bf1 = *(const bf16x8*)(smem + (b1 ^ ((unsigned)(j1 & 7) << 4)));
        accS1 = __builtin_amdgcn_mfma_f32_16x16x32_bf16(af, bf1, accS1, 0, 0, 0);
    }
    __syncthreads();   // sync2: S done, su/sh/Ujt ready

    // ---- softmax over j (C layout: row=(lane>>4)*4+r, col=lane&15) ----
    const int rowBase = rg * 16 + ((lane >> 4) << 2);
    const float su0 = *(const float*)(smem + OFF_SUS + (unsigned)(cgS * 32 + (lane & 15)) * 4u);
    const float su1 = *(const float*)(smem + OFF_SUS + (unsigned)(cgS * 32 + 16 + (lane & 15)) * 4u);
    f32x4 sh4 = *(const f32x4*)(smem + OFF_SHS + (unsigned)rowBase * 4u);
    float s0a[4], s1a[4], e0a[4], e1a[4];
    #pragma unroll
    for (int r = 0; r < 4; ++r) {
        float s0 = accS0[r] + sh4[r] + su0;
        float s1 = accS1[r] + sh4[r] + su1;
        s0a[r] = s0; s1a[r] = s1;
        float m = fmaxf(s0, s1);
        m = fmaxf(m, __shfl_xor(m, 1));
        m = fmaxf(m, __shfl_xor(m, 2));
        m = fmaxf(m, __shfl_xor(m, 4));
        m = fmaxf(m, __shfl_xor(m, 8));
        if ((lane & 15) == 0)
            *(float*)(smem + OFF_SMX + (unsigned)((rowBase + r) * 4 + cgS) * 4u) = m;
    }
    __syncthreads();
    #pragma unroll
    for (int r = 0; r < 4; ++r) {
        f32x4 mx4 = *(const f32x4*)(smem + OFF_SMX + (unsigned)(rowBase + r) * 16u);
        float M = fmaxf(fmaxf(mx4[0], mx4[1]), fmaxf(mx4[2], mx4[3]));
        float e0 = __expf(s0a[r] - M), e1 = __expf(s1a[r] - M);
        e0a[r] = e0; e1a[r] = e1;
        float s = e0 + e1;
        s += __shfl_xor(s, 1); s += __shfl_xor(s, 2);
        s += __shfl_xor(s, 4); s += __shfl_xor(s, 8);
        if ((lane & 15) == 0)
            *(float*)(smem + OFF_SSM + (unsigned)((rowBase + r) * 4 + cgS) * 4u) = s;
        if (cgS == 0 && (lane & 15) == 0)
            mrow[(size_t)b * Tt + t0 + rowBase + r] = M;
    }
    __syncthreads();
    #pragma unroll
    for (int r = 0; r < 4; ++r) {
        f32x4 sm4 = *(const f32x4*)(smem + OFF_SSM + (unsigned)(rowBase + r) * 16u);
        float inv = 1.f / (sm4[0] + sm4[1] + sm4[2] + sm4[3]);
        float p0 = e0a[r] * inv, p1 = e1a[r] * inv;
        float pn0 = __shfl_down(p0, 1), pn1 = __shfl_down(p1, 1);
        if (!(lane & 1)) {
            int row = rowBase + r;
            int col0 = cgS * 32 + (lane & 15);
            unsigned swz = (unsigned)(row & 7) << 4;
            unsigned a0 = OFF_PSH + (unsigned)row * 256u + (unsigned)col0 * 2u;
            *(unsigned*)(smem + (a0 ^ swz)) = (unsigned)f2bf(p0) | ((unsigned)f2bf(pn0) << 16);
            unsigned a1 = a0 + 32u;
            *(unsigned*)(smem + (a1 ^ swz)) = (unsigned)f2bf(p1) | ((unsigned)f2bf(pn1) << 16);
        }
    }
    __syncthreads();   // sync3: P ready

    // ---- PV phase: U_tilde = P . U ; wave (rg2,cg2): rows rg2*16, tiles of 16 d ----
    const int rg2 = wv >> 2, cg2 = wv & 3;
    const int start = (cg2 == 0) ? 0 : (3 * cg2 + 1);   // {0,4,7,10}
    const int cnt   = (cg2 == 0) ? 4 : 3;
    const int rowA2 = rg2 * 16 + (lane & 15);
    f32x4 accP0 = {0.f,0.f,0.f,0.f}, accP1 = {0.f,0.f,0.f,0.f};
    f32x4 accP2 = {0.f,0.f,0.f,0.f}, accP3 = {0.f,0.f,0.f,0.f};
    #pragma unroll
    for (int ki = 0; ki < 4; ++ki) {
        unsigned ab = OFF_PSH + (unsigned)rowA2 * 256u + (unsigned)ki * 64u + kfo;
        bf16x8 af = *(const bf16x8*)(smem + (ab ^ ((unsigned)(rowA2 & 7) << 4)));
        int d0 = start * 16 + (lane & 15);
        {
            unsigned bb0 = OFF_UJT + (unsigned)d0 * 256u + (unsigned)ki * 64u + kfo;
            bf16x8 bf = *(const bf16x8*)(smem + (bb0 ^ ((unsigned)(d0 & 7) << 4)));
            accP0 = __builtin_amdgcn_mfma_f32_16x16x32_bf16(af, bf, accP0, 0, 0, 0);
        }
        {
            int d = d0 + 16;
            unsigned bb1 = OFF_UJT + (unsigned)d * 256u + (unsigned)ki * 64u + kfo;
            bf16x8 bf = *(const bf16x8*)(smem + (bb1 ^ ((unsigned)(d & 7) << 4)));
            accP1 = __builtin_amdgcn_mfma_f32_16x16x32_bf16(af, bf, accP1, 0, 0, 0);
        }
        {
            int d = d0 + 32;
            unsigned bb2 = OFF_UJT + (unsigned)d * 256u + (unsigned)ki * 64u + kfo;
            bf16x8 bf = *(const bf16x8*)(smem + (bb2 ^ ((unsigned)(d & 7) << 4)));
            accP2 = __builtin_amdgcn_mfma_f32_16x16x32_bf16(af, bf, accP2, 0, 0, 0);
        }
        if (cnt == 4) {
            int d = d0 + 48;
            unsigned bb3 = OFF_UJT + (unsigned)d * 256u + (unsigned)ki * 64u + kfo;
            bf16x8 bf = *(const bf16x8*)(smem + (bb3 ^ ((unsigned)(d & 7) << 4)));
            accP3 = __builtin_amdgcn_mfma_f32_16x16x32_bf16(af, bf, accP3, 0, 0, 0);
        }
    }
    __syncthreads();   // sync4: PV done, Ujt region reusable

    // ---- stage U_tilde f32 into UTSH (overlay of Ujt): [64][204] stride 816 ----
    // GUARD every store with col < Dd: cg2==3's third tile covers d=192..207 and
    // cols 204..207 would otherwise overflow into row+1's cols 0..3 (the round-2 bug).
    {
        const int rowW = rg2 * 16 + ((lane >> 4) << 2);
        const int c0 = start * 16 + (lane & 15);
        #pragma unroll
        for (int r = 0; r < 4; ++r) {
            int row = rowW + r;
            float* base = (float*)(smem + OFF_UJT + (unsigned)row * 816u);
            base[c0]      = accP0[r];
            base[c0 + 16] = accP1[r];
            if (c0 + 32 < Dd) base[c0 + 32] = accP2[r];
            if (cnt == 4)     base[c0 + 48] = accP3[r];
        }
    }
    __syncthreads();   // sync5: UTSH ready

    // ---- epilogue: coalesced float4 writes of G[:,0:600] ----
    for (int i = tid; i < TILE * 50; i += NTH) {
        int row = i / 50, c = i % 50;
        f32x4 ut = *(const f32x4*)(smem + OFF_UJT + (unsigned)row * 816u + (unsigned)c * 16u);
        f32x4 h4 = *(const f32x4*)(Hb + row * Dd + c * 4);
        float* grow = G + ((size_t)b * Tt + t0 + row) * GD + c * 4;
        *(f32x4*)(grow)       = h4;
        *(f32x4*)(grow + 200) = ut;
        *(f32x4*)(grow + 400) = h4 * ut;
    }
}

// ---------------------------------------------------------------------------
// K2a: q[b,:] = softmax over t of m[b,:]
// ---------------------------------------------------------------------------
__global__ __launch_bounds__(256) void k_q(
    const float* __restrict__ mrow, float* __restrict__ q)
{
    __shared__ float red[4];
    __shared__ float sM, sS;
    const int b = blockIdx.x, tid = threadIdx.x;
    const int lane = tid & 63, wv = tid >> 6;
    const float* mb = mrow + (size_t)b * Tt;

    float lm = -1e30f;
    for (int i = tid; i < Tt; i += 256) lm = fmaxf(lm, mb[i]);
    #pragma unroll
    for (int off = 32; off; off >>= 1) lm = fmaxf(lm, __shfl_xor(lm, off));
    if (lane == 0) red[wv] = lm;
    __syncthreads();
    if (tid == 0) sM = fmaxf(fmaxf(red[0], red[1]), fmaxf(red[2], red[3]));
    __syncthreads();
    const float M = sM;

    float ls = 0.f;
    for (int i = tid; i < Tt; i += 256) ls += __expf(mb[i] - M);
    #pragma unroll
    for (int off = 32; off; off >>= 1) ls += __shfl_xor(ls, off);
    __syncthreads();
    if (lane == 0) red[wv] = ls;
    __syncthreads();
    if (tid == 0) sS = red[0] + red[1] + red[2] + red[3];
    __syncthreads();
    const float invS = 1.f / sS;

    for (int i = tid; i < Tt; i += 256)
        q[(size_t)b * Tt + i] = __expf(mb[i] - M) * invS;
}

// ---------------------------------------------------------------------------
// K2b: htil[b,d] = sum_t q[b,t] * H[b,t,d]  (float4, atomic partials)
// ---------------------------------------------------------------------------
__global__ __launch_bounds__(256) void k_ht(
    const float* __restrict__ H, const float* __restrict__ q,
    float* __restrict__ htil)
{
    const int b = blockIdx.y, ch = blockIdx.x;
    const int d4 = threadIdx.x & 63;
    const int tp = threadIdx.x >> 6;
    if (d4 >= 50) return;
    const float* Hb = H + (size_t)b * Tt * Dd;
    const float* qb = q + (size_t)b * Tt;
    f32x4 acc = {0.f, 0.f, 0.f, 0.f};
    const int tbase = ch * 128 + tp * 32;
    for (int k = 0; k < 32; ++k) {
        int t = tbase + k;
        f32x4 h4 = *(const f32x4*)(Hb + (size_t)t * Dd + d4 * 4);
        acc += h4 * qb[t];
    }
    float* hp = htil + b * Dd + d4 * 4;
    atomicAdd(hp + 0, acc[0]); atomicAdd(hp + 1, acc[1]);
    atomicAdd(hp + 2, acc[2]); atomicAdd(hp + 3, acc[3]);
}

// ---------------------------------------------------------------------------
// K3: G[:,600:800] = H * htil[b,:]
// ---------------------------------------------------------------------------
__global__ __launch_bounds__(256) void k_g3(
    const float* __restrict__ H, const float* __restrict__ htil,
    float* __restrict__ G)
{
    const int idx = blockIdx.x * 256 + threadIdx.x;
    if (idx >= Bb * Tt * Dd) return;
    const int d  = idx % Dd;
    const int bt = idx / Dd;
    const int b  = bt >> 11;
    G[(size_t)bt * GD + 600 + d] = H[idx] * htil[b * Dd + d];
}

// ---------------------------------------------------------------------------
extern "C" void kernel_launch(void* const* d_in, const int* in_sizes, int n_in,
                              void* d_out, int out_size, void* d_ws, size_t ws_size,
                              hipStream_t stream)
{
    const float* H    = (const float*)d_in[0];
    const float* U    = (const float*)d_in[1];
    const float* wt   = (const float*)d_in[2];
    const float* bptr = (const float*)d_in[3];

    float* G    = (float*)d_out;
    float* q    = G + (size_t)Bb * Tt * GD;     // output 1 region
    float* mrow = (float*)d_ws;                 // B*T floats
    float* htil = mrow + (size_t)Bb * Tt;       // B*Dd floats

    hipMemsetAsync(htil, 0, (size_t)Bb * Dd * sizeof(float), stream);

    k_main<<<(Tt / TILE) * Bb, NTH, 0, stream>>>(H, U, wt, bptr, G, mrow);

    k_q<<<Bb, 256, 0, stream>>>(mrow, q);

    dim3 g2(Tt / 128, Bb);
    k_ht<<<g2, 256, 0, stream>>>(H, q, htil);

    const int n3 = Bb * Tt * Dd;
    k_g3<<<(n3 + 255) / 256, 256, 0, stream>>>(H, htil, G);
}

// Round 4
// 642.537 us; speedup vs baseline: 1.7700x; 1.1085x over previous
//
#include <hip/hip_runtime.h>
#include <math.h>

typedef __attribute__((ext_vector_type(8))) short bf16x8;
typedef __attribute__((ext_vector_type(4))) float f32x4;

#define Bb 64
#define Tt 2048
#define Jj 128
#define Dd 200
#define GD 800
#define TILE 32            // t-rows per tile
#define NT 16              // tiles per block -> 512 rows/block
#define ROWS_BLK (TILE*NT)
#define NTH 1024

// LDS byte offsets (all 256-aligned; XOR-bit-4 swizzle stays in-region)
#define OFF_USH 0u         // [128][224] bf16, stride 448  (U, d-contiguous)
#define OFF_UJT 57344u     // [208][128] bf16, stride 256  (U^T, j-contiguous)
#define OFF_HMS 110592u    // 2 x [32][224] bf16, stride 448 (H*wm, dbuf, 14336 each)
#define OFF_PSH 139264u    // [32][128] bf16, stride 256   (P)
#define OFF_SUS 147456u    // [128] f32  su[j] = wu.U_j + b
#define OFF_SHS 147968u    // 2 x [32] f32  sh[t] (dbuf)
#define OFF_SMX 148224u    // [32][8] f32 per-cg partial row max
#define OFF_SSM 149248u    // [32][8] f32 per-cg partial row sum
#define SMEM_BYTES 150272u

__device__ __forceinline__ unsigned short f2bf(float f) {
    union { float f; unsigned u; } v; v.f = f;
    unsigned r = v.u + 0x7FFFu + ((v.u >> 16) & 1u);
    return (unsigned short)(r >> 16);
}

__device__ __forceinline__ bf16x8 pack8(f32x4 a, f32x4 b) {
    bf16x8 o;
    o[0] = (short)f2bf(a[0]); o[1] = (short)f2bf(a[1]);
    o[2] = (short)f2bf(a[2]); o[3] = (short)f2bf(a[3]);
    o[4] = (short)f2bf(b[0]); o[5] = (short)f2bf(b[1]);
    o[6] = (short)f2bf(b[2]); o[7] = (short)f2bf(b[3]);
    return o;
}

// Stage one 32-row H tile: Hms[buf] = bf16(H*wm) (swizzled), sh[buf][row] = dot(H_row, wh).
// Thread map: row = tid>>5 (32 rows), c = tid&31 (8-elem chunk; c<25 real, 25..27 zero-pad).
__device__ __forceinline__ void stage_h(char* smem, const float* __restrict__ Hrows,
                                        int tid, int buf,
                                        f32x4 wmA, f32x4 wmB, f32x4 whA, f32x4 whB)
{
    const int row = tid >> 5, c = tid & 31;
    float shp = 0.f;
    bf16x8 val = {0,0,0,0,0,0,0,0};
    if (c < 25) {
        const float* p = Hrows + row * Dd + c * 8;
        f32x4 h0 = *(const f32x4*)p, h1 = *(const f32x4*)(p + 4);
        shp = h0[0]*whA[0] + h0[1]*whA[1] + h0[2]*whA[2] + h0[3]*whA[3]
            + h1[0]*whB[0] + h1[1]*whB[1] + h1[2]*whB[2] + h1[3]*whB[3];
        val = pack8(h0 * wmA, h1 * wmB);
    }
    if (c < 28) {
        unsigned a = OFF_HMS + (unsigned)buf * 14336u + (unsigned)row * 448u + (unsigned)c * 16u;
        *(bf16x8*)(smem + (a ^ ((unsigned)(row & 7) << 4))) = val;
    }
    #pragma unroll
    for (int off = 16; off; off >>= 1) shp += __shfl_xor(shp, off);
    if ((tid & 31) == 0)
        *(float*)(smem + OFF_SHS + (unsigned)buf * 128u + (unsigned)row * 4u) = shp;
}

// ---------------------------------------------------------------------------
// K1: persistent-tile fused S -> softmax -> U_tilde; writes G[:,0:600], mrow
// ---------------------------------------------------------------------------
__global__ __launch_bounds__(NTH) void k_main(
    const float* __restrict__ H, const float* __restrict__ U,
    const float* __restrict__ wt, const float* __restrict__ bptr,
    float* __restrict__ G, float* __restrict__ mrow)
{
    __shared__ __align__(16) char smem[SMEM_BYTES];

    const int tid  = threadIdx.x;
    const int lane = tid & 63;
    const int wv   = tid >> 6;          // wave 0..15

    // XCD swizzle: 256 blocks -> 8 XCDs x 32 contiguous (bijective)
    const int swz = ((blockIdx.x & 7) << 5) | (blockIdx.x >> 3);
    const int b   = swz >> 2;            // 4 blocks per batch
    const int t0  = (swz & 3) * ROWS_BLK;

    const float* Hb = H + ((size_t)b * Tt + t0) * Dd;
    const float* Ub = U + (size_t)b * Jj * Dd;
    const float  bb = bptr[0];

    // per-thread weight fragments for stage_h (chunk cc = tid&31)
    const int cc = tid & 31;
    f32x4 whA = {0,0,0,0}, whB = {0,0,0,0}, wmA = {0,0,0,0}, wmB = {0,0,0,0};
    if (cc < 25) {
        whA = *(const f32x4*)(wt + cc * 8);       whB = *(const f32x4*)(wt + cc * 8 + 4);
        wmA = *(const f32x4*)(wt + 400 + cc * 8); wmB = *(const f32x4*)(wt + 400 + cc * 8 + 4);
    }
    // su-pass weights (full-wave layout)
    const float wu0 = wt[200 + lane], wu1 = wt[264 + lane], wu2 = wt[328 + lane];
    const float wu3 = (lane < 8) ? wt[392 + lane] : 0.f;

    // ---- prologue: stage U (bf16, swizzled) ----
    for (int i = tid; i < 128 * 28; i += NTH) {
        int row = i / 28, c8 = i % 28;
        bf16x8 val = {0,0,0,0,0,0,0,0};
        if (c8 < 25) {
            const float* p = Ub + row * Dd + c8 * 8;
            val = pack8(*(const f32x4*)p, *(const f32x4*)(p + 4));
        }
        unsigned a = OFF_USH + (unsigned)row * 448u + (unsigned)c8 * 16u;
        *(bf16x8*)(smem + (a ^ ((unsigned)(row & 7) << 4))) = val;
    }
    // stage Hms[0] + sh[0]
    stage_h(smem, Hb, tid, 0, wmA, wmB, whA, whB);
    // su[j] = dot(U_j, wu) + b  (from global, once per block)
    for (int jj = 0; jj < 8; ++jj) {
        int j = wv * 8 + jj;
        const float* up = Ub + j * Dd;
        float v = up[lane] * wu0 + up[64 + lane] * wu1 + up[128 + lane] * wu2;
        if (lane < 8) v += up[192 + lane] * wu3;
        #pragma unroll
        for (int off = 32; off; off >>= 1) v += __shfl_xor(v, off);
        if (lane == 0) *(float*)(smem + OFF_SUS + (unsigned)j * 4u) = v + bb;
    }
    __syncthreads();   // prologue barrier: Ush/Hms0/sh0/su ready

    // build Ujt[d][j] = Ush[j][d] (bf16, swizzled), zero rows for d>=200
    for (int i = tid; i < 208 * 64; i += NTH) {
        int d  = i >> 6;
        int jp = (i & 63) << 1;
        unsigned short v0 = 0, v1 = 0;
        if (d < Dd) {
            unsigned a0 = OFF_USH + (unsigned)jp * 448u + ((unsigned)d << 1);
            v0 = *(const unsigned short*)(smem + (a0 ^ ((unsigned)(jp & 7) << 4)));
            unsigned a1 = OFF_USH + (unsigned)(jp + 1) * 448u + ((unsigned)d << 1);
            v1 = *(const unsigned short*)(smem + (a1 ^ ((unsigned)((jp + 1) & 7) << 4)));
        }
        unsigned pk = (unsigned)v0 | ((unsigned)v1 << 16);
        unsigned wa = OFF_UJT + (unsigned)d * 256u + (unsigned)((i & 63) << 2);
        *(unsigned*)(smem + (wa ^ ((unsigned)(d & 7) << 4))) = pk;
    }
    // (Ujt consumed only after this tile's B1/B2/B3 barriers -> no extra barrier)

    // wave geometry: 2 row-groups x 8 col-groups
    const int rg  = wv >> 3;                 // 0..1
    const int cg  = wv & 7;                  // 0..7
    const int l15 = lane & 15;
    const int lq  = lane >> 4;               // quarter 0..3
    const unsigned kfo = (unsigned)(lq << 4);       // byte k-offset within fragment
    const int rowA    = rg * 16 + l15;       // A-fragment row
    const int rowBase = rg * 16 + (lq << 2); // C-fragment row base
    const int jcol    = cg * 16 + l15;       // S-phase column (j)
    // PV d-tile assignment: {cg, cg+8}, skip >=13
    const int  dt0  = cg, dt1 = cg + 8;
    const bool has2 = (dt1 < 13);
    const int  dcol0 = dt0 * 16 + l15;
    const int  dcol1 = dt1 * 16 + l15;

    const unsigned hswz = (unsigned)(rowA & 7) << 4;
    const unsigned ubase = OFF_USH + (unsigned)jcol * 448u;
    const unsigned uswz  = (unsigned)(jcol & 7) << 4;
    const unsigned pbase = OFF_PSH + (unsigned)rowA * 256u;
    const unsigned pswz  = (unsigned)(rowA & 7) << 4;

    for (int tile = 0; tile < NT; ++tile) {
        const int cur = tile & 1, nxt = cur ^ 1;
        const float* Ht = Hb + (size_t)tile * TILE * Dd;

        // prefetch next tile's Hms + sh (loads issue now, hide under S+softmax)
        if (tile + 1 < NT)
            stage_h(smem, Ht + TILE * Dd, tid, nxt, wmA, wmB, whA, whB);

        // ---- S MFMA ----
        f32x4 acc = {0.f, 0.f, 0.f, 0.f};
        const unsigned hbase = OFF_HMS + (unsigned)cur * 14336u + (unsigned)rowA * 448u;
        #pragma unroll
        for (int ki = 0; ki < 7; ++ki) {
            bf16x8 af = *(const bf16x8*)(smem + ((hbase + (unsigned)ki * 64u + kfo) ^ hswz));
            bf16x8 bf = *(const bf16x8*)(smem + ((ubase + (unsigned)ki * 64u + kfo) ^ uswz));
            acc = __builtin_amdgcn_mfma_f32_16x16x32_bf16(af, bf, acc, 0, 0, 0);
        }

        // ---- softmax over j ----
        const float suv = *(const float*)(smem + OFF_SUS + (unsigned)jcol * 4u);
        f32x4 sh4 = *(const f32x4*)(smem + OFF_SHS + (unsigned)cur * 128u + (unsigned)rowBase * 4u);
        float sv[4], ev[4], Mv[4];
        #pragma unroll
        for (int r = 0; r < 4; ++r) {
            float s = acc[r] + sh4[r] + suv;
            sv[r] = s;
            float m = s;
            m = fmaxf(m, __shfl_xor(m, 1));
            m = fmaxf(m, __shfl_xor(m, 2));
            m = fmaxf(m, __shfl_xor(m, 4));
            m = fmaxf(m, __shfl_xor(m, 8));
            if (l15 == 0)
                *(float*)(smem + OFF_SMX + (unsigned)((rowBase + r) * 8 + cg) * 4u) = m;
        }
        __syncthreads();   // B1
        #pragma unroll
        for (int r = 0; r < 4; ++r) {
            f32x4 ma = *(const f32x4*)(smem + OFF_SMX + (unsigned)(rowBase + r) * 32u);
            f32x4 mb2 = *(const f32x4*)(smem + OFF_SMX + (unsigned)(rowBase + r) * 32u + 16u);
            float M = fmaxf(fmaxf(fmaxf(ma[0], ma[1]), fmaxf(ma[2], ma[3])),
                            fmaxf(fmaxf(mb2[0], mb2[1]), fmaxf(mb2[2], mb2[3])));
            Mv[r] = M;
            float e = __expf(sv[r] - M);
            ev[r] = e;
            float ssum = e;
            ssum += __shfl_xor(ssum, 1); ssum += __shfl_xor(ssum, 2);
            ssum += __shfl_xor(ssum, 4); ssum += __shfl_xor(ssum, 8);
            if (l15 == 0)
                *(float*)(smem + OFF_SSM + (unsigned)((rowBase + r) * 8 + cg) * 4u) = ssum;
        }
        if (cg == 0 && l15 == 0) {
            #pragma unroll
            for (int r = 0; r < 4; ++r)
                mrow[(size_t)b * Tt + t0 + tile * TILE + rowBase + r] = Mv[r];
        }
        __syncthreads();   // B2
        #pragma unroll
        for (int r = 0; r < 4; ++r) {
            f32x4 sa = *(const f32x4*)(smem + OFF_SSM + (unsigned)(rowBase + r) * 32u);
            f32x4 sb = *(const f32x4*)(smem + OFF_SSM + (unsigned)(rowBase + r) * 32u + 16u);
            float inv = 1.f / (sa[0] + sa[1] + sa[2] + sa[3] + sb[0] + sb[1] + sb[2] + sb[3]);
            float p  = ev[r] * inv;
            float pn = __shfl_down(p, 1);
            if (!(lane & 1)) {
                int row = rowBase + r;
                unsigned a0 = OFF_PSH + (unsigned)row * 256u + (unsigned)jcol * 2u;
                *(unsigned*)(smem + (a0 ^ ((unsigned)(row & 7) << 4))) =
                    (unsigned)f2bf(p) | ((unsigned)f2bf(pn) << 16);
            }
        }
        __syncthreads();   // B3: P ready

        // ---- PV MFMA ----
        f32x4 acc0 = {0.f,0.f,0.f,0.f}, acc1 = {0.f,0.f,0.f,0.f};
        #pragma unroll
        for (int ki = 0; ki < 4; ++ki) {
            bf16x8 af = *(const bf16x8*)(smem + ((pbase + (unsigned)ki * 64u + kfo) ^ pswz));
            bf16x8 b0 = *(const bf16x8*)(smem +
                ((OFF_UJT + (unsigned)dcol0 * 256u + (unsigned)ki * 64u + kfo) ^ ((unsigned)(dcol0 & 7) << 4)));
            acc0 = __builtin_amdgcn_mfma_f32_16x16x32_bf16(af, b0, acc0, 0, 0, 0);
            if (has2) {
                bf16x8 b1 = *(const bf16x8*)(smem +
                    ((OFF_UJT + (unsigned)dcol1 * 256u + (unsigned)ki * 64u + kfo) ^ ((unsigned)(dcol1 & 7) << 4)));
                acc1 = __builtin_amdgcn_mfma_f32_16x16x32_bf16(af, b1, acc1, 0, 0, 0);
            }
        }

        // ---- epilogue: direct G writes from registers ----
        float* Gtile = G + ((size_t)b * Tt + t0 + tile * TILE) * GD;
        #pragma unroll
        for (int r = 0; r < 4; ++r) {
            int row = rowBase + r;
            float* grow = Gtile + (size_t)row * GD;
            {
                float ut = acc0[r];
                float h  = Ht[row * Dd + dcol0];
                grow[200 + dcol0] = ut;
                grow[400 + dcol0] = h * ut;
            }
            if (has2 && dcol1 < Dd) {
                float ut = acc1[r];
                float h  = Ht[row * Dd + dcol1];
                grow[200 + dcol1] = ut;
                grow[400 + dcol1] = h * ut;
            }
        }
        // H copy G[:,0:200] (f32x4 coalesced; reads are L2-hot)
        for (int i = tid; i < TILE * 50; i += NTH) {
            int row = i / 50, c = i % 50;
            f32x4 h4 = *(const f32x4*)(Ht + row * Dd + c * 4);
            *(f32x4*)(Gtile + (size_t)row * GD + c * 4) = h4;
        }
        // no end barrier: next tile's B1 orders all LDS reuse (PSH/Hms/sh)
    }
}

// ---------------------------------------------------------------------------
// K2a: q[b,:] = softmax over t of m[b,:]
// ---------------------------------------------------------------------------
__global__ __launch_bounds__(256) void k_q(
    const float* __restrict__ mrow, float* __restrict__ q)
{
    __shared__ float red[4];
    __shared__ float sM, sS;
    const int b = blockIdx.x, tid = threadIdx.x;
    const int lane = tid & 63, wv = tid >> 6;
    const float* mb = mrow + (size_t)b * Tt;

    float lm = -1e30f;
    for (int i = tid; i < Tt; i += 256) lm = fmaxf(lm, mb[i]);
    #pragma unroll
    for (int off = 32; off; off >>= 1) lm = fmaxf(lm, __shfl_xor(lm, off));
    if (lane == 0) red[wv] = lm;
    __syncthreads();
    if (tid == 0) sM = fmaxf(fmaxf(red[0], red[1]), fmaxf(red[2], red[3]));
    __syncthreads();
    const float M = sM;

    float ls = 0.f;
    for (int i = tid; i < Tt; i += 256) ls += __expf(mb[i] - M);
    #pragma unroll
    for (int off = 32; off; off >>= 1) ls += __shfl_xor(ls, off);
    __syncthreads();
    if (lane == 0) red[wv] = ls;
    __syncthreads();
    if (tid == 0) sS = red[0] + red[1] + red[2] + red[3];
    __syncthreads();
    const float invS = 1.f / sS;

    for (int i = tid; i < Tt; i += 256)
        q[(size_t)b * Tt + i] = __expf(mb[i] - M) * invS;
}

// ---------------------------------------------------------------------------
// K2b: htil[b,d] = sum_t q[b,t] * H[b,t,d]  (float4, atomic partials)
// ---------------------------------------------------------------------------
__global__ __launch_bounds__(256) void k_ht(
    const float* __restrict__ H, const float* __restrict__ q,
    float* __restrict__ htil)
{
    const int b = blockIdx.y, ch = blockIdx.x;
    const int d4 = threadIdx.x & 63;
    const int tp = threadIdx.x >> 6;
    if (d4 >= 50) return;
    const float* Hb = H + (size_t)b * Tt * Dd;
    const float* qb = q + (size_t)b * Tt;
    f32x4 acc = {0.f, 0.f, 0.f, 0.f};
    const int tbase = ch * 128 + tp * 32;
    for (int k = 0; k < 32; ++k) {
        int t = tbase + k;
        f32x4 h4 = *(const f32x4*)(Hb + (size_t)t * Dd + d4 * 4);
        acc += h4 * qb[t];
    }
    float* hp = htil + b * Dd + d4 * 4;
    atomicAdd(hp + 0, acc[0]); atomicAdd(hp + 1, acc[1]);
    atomicAdd(hp + 2, acc[2]); atomicAdd(hp + 3, acc[3]);
}

// ---------------------------------------------------------------------------
// K3: G[:,600:800] = H * htil[b,:]   (f32x4 vectorized)
// ---------------------------------------------------------------------------
__global__ __launch_bounds__(256) void k_g3(
    const float* __restrict__ H, const float* __restrict__ htil,
    float* __restrict__ G)
{
    const int idx = blockIdx.x * 256 + threadIdx.x;   // over Bb*Tt*50 f32x4 chunks
    if (idx >= Bb * Tt * 50) return;
    const int d4 = idx % 50;
    const int bt = idx / 50;
    const int b  = bt >> 11;
    f32x4 h4 = *(const f32x4*)(H + (size_t)bt * Dd + d4 * 4);
    f32x4 t4 = *(const f32x4*)(htil + b * Dd + d4 * 4);
    *(f32x4*)(G + (size_t)bt * GD + 600 + d4 * 4) = h4 * t4;
}

// ---------------------------------------------------------------------------
extern "C" void kernel_launch(void* const* d_in, const int* in_sizes, int n_in,
                              void* d_out, int out_size, void* d_ws, size_t ws_size,
                              hipStream_t stream)
{
    const float* H    = (const float*)d_in[0];
    const float* U    = (const float*)d_in[1];
    const float* wt   = (const float*)d_in[2];
    const float* bptr = (const float*)d_in[3];

    float* G    = (float*)d_out;
    float* q    = G + (size_t)Bb * Tt * GD;     // output 1 region
    float* mrow = (float*)d_ws;                 // B*T floats
    float* htil = mrow + (size_t)Bb * Tt;       // B*Dd floats

    hipMemsetAsync(htil, 0, (size_t)Bb * Dd * sizeof(float), stream);

    k_main<<<(Bb * Tt / ROWS_BLK), NTH, 0, stream>>>(H, U, wt, bptr, G, mrow);

    k_q<<<Bb, 256, 0, stream>>>(mrow, q);

    dim3 g2(Tt / 128, Bb);
    k_ht<<<g2, 256, 0, stream>>>(H, q, htil);

    const int n3 = Bb * Tt * 50;
    k_g3<<<(n3 + 255) / 256, 256, 0, stream>>>(H, htil, G);
}

// Round 5
// 596.275 us; speedup vs baseline: 1.9073x; 1.0776x over previous
//
#include <hip/hip_runtime.h>
#include <math.h>

typedef __attribute__((ext_vector_type(8))) short bf16x8;
typedef __attribute__((ext_vector_type(4))) float f32x4;

#define Bb 64
#define Tt 2048
#define Jj 128
#define Dd 200
#define GD 800
#define TILE 32            // t-rows per tile
#define NT 16              // tiles per block -> 512 rows/block
#define ROWS_BLK (TILE*NT)
#define NTH 1024

// LDS byte offsets (all 256-aligned; XOR-bit-4 swizzle stays in-region)
#define OFF_USH 0u         // [128][224] bf16, stride 448  (U, d-contiguous)
#define OFF_UJT 57344u     // [208][128] bf16, stride 256  (U^T, j-contiguous)
#define OFF_HMS 110592u    // 2 x [32][224] bf16, stride 448 (H*wm, dbuf, 14336 each)
#define OFF_PSH 139264u    // [32][128] bf16, stride 256   (P)
#define OFF_SUS 147456u    // [128] f32  su[j] = wu.U_j + b
#define OFF_SHS 147968u    // 2 x [32] f32  sh[t] (dbuf)
#define OFF_SMX 148224u    // [32][8] f32 per-cg partial row max
#define OFF_SSM 149248u    // [32][8] f32 per-cg partial row sum
#define SMEM_BYTES 150272u

__device__ __forceinline__ unsigned short f2bf(float f) {
    union { float f; unsigned u; } v; v.f = f;
    unsigned r = v.u + 0x7FFFu + ((v.u >> 16) & 1u);
    return (unsigned short)(r >> 16);
}

__device__ __forceinline__ bf16x8 pack8(f32x4 a, f32x4 b) {
    bf16x8 o;
    o[0] = (short)f2bf(a[0]); o[1] = (short)f2bf(a[1]);
    o[2] = (short)f2bf(a[2]); o[3] = (short)f2bf(a[3]);
    o[4] = (short)f2bf(b[0]); o[5] = (short)f2bf(b[1]);
    o[6] = (short)f2bf(b[2]); o[7] = (short)f2bf(b[3]);
    return o;
}

// Raw barrier: orders LDS only (lgkmcnt(0)), leaves global stores in flight.
// asm memory clobbers on both sides stop the compiler moving LDS/global ops across.
__device__ __forceinline__ void bar_lds() {
    asm volatile("s_waitcnt lgkmcnt(0)" ::: "memory");
    __builtin_amdgcn_s_barrier();
    asm volatile("" ::: "memory");
}

// --- staging split (T14): loads at tile top, LDS writes at tile bottom ---
__device__ __forceinline__ void stage_load(const float* __restrict__ Hrows, int tid,
                                           f32x4& h0, f32x4& h1)
{
    const int row = tid >> 5, c = tid & 31;
    if (c < 25) {
        const float* p = Hrows + row * Dd + c * 8;
        h0 = *(const f32x4*)p;
        h1 = *(const f32x4*)(p + 4);
    }
}

__device__ __forceinline__ void stage_write(char* smem, int tid, int buf,
                                            f32x4 h0, f32x4 h1,
                                            f32x4 wmA, f32x4 wmB, f32x4 whA, f32x4 whB)
{
    const int row = tid >> 5, c = tid & 31;
    float shp = 0.f;
    bf16x8 val = {0,0,0,0,0,0,0,0};
    if (c < 25) {
        shp = h0[0]*whA[0] + h0[1]*whA[1] + h0[2]*whA[2] + h0[3]*whA[3]
            + h1[0]*whB[0] + h1[1]*whB[1] + h1[2]*whB[2] + h1[3]*whB[3];
        val = pack8(h0 * wmA, h1 * wmB);
    }
    if (c < 28) {
        unsigned a = OFF_HMS + (unsigned)buf * 14336u + (unsigned)row * 448u + (unsigned)c * 16u;
        *(bf16x8*)(smem + (a ^ ((unsigned)(row & 7) << 4))) = val;
    }
    #pragma unroll
    for (int off = 16; off; off >>= 1) shp += __shfl_xor(shp, off);
    if ((tid & 31) == 0)
        *(float*)(smem + OFF_SHS + (unsigned)buf * 128u + (unsigned)row * 4u) = shp;
}

// ---------------------------------------------------------------------------
// K1: persistent-tile fused S -> softmax -> U_tilde; writes G[:,0:600], mrow
// ---------------------------------------------------------------------------
__global__ __launch_bounds__(NTH) void k_main(
    const float* __restrict__ H, const float* __restrict__ U,
    const float* __restrict__ wt, const float* __restrict__ bptr,
    float* __restrict__ G, float* __restrict__ mrow)
{
    __shared__ __align__(16) char smem[SMEM_BYTES];

    const int tid  = threadIdx.x;
    const int lane = tid & 63;
    const int wv   = tid >> 6;          // wave 0..15

    // XCD swizzle: 256 blocks -> 8 XCDs x 32 contiguous (bijective)
    const int swz = ((blockIdx.x & 7) << 5) | (blockIdx.x >> 3);
    const int b   = swz >> 2;            // 4 blocks per batch
    const int t0  = (swz & 3) * ROWS_BLK;

    const float* Hb = H + ((size_t)b * Tt + t0) * Dd;
    const float* Ub = U + (size_t)b * Jj * Dd;
    const float  bb = bptr[0];

    // per-thread weight fragments for staging (chunk cc = tid&31)
    const int cc = tid & 31;
    f32x4 whA = {0,0,0,0}, whB = {0,0,0,0}, wmA = {0,0,0,0}, wmB = {0,0,0,0};
    if (cc < 25) {
        whA = *(const f32x4*)(wt + cc * 8);       whB = *(const f32x4*)(wt + cc * 8 + 4);
        wmA = *(const f32x4*)(wt + 400 + cc * 8); wmB = *(const f32x4*)(wt + 400 + cc * 8 + 4);
    }
    // su-pass weights (full-wave layout)
    const float wu0 = wt[200 + lane], wu1 = wt[264 + lane], wu2 = wt[328 + lane];
    const float wu3 = (lane < 8) ? wt[392 + lane] : 0.f;

    // ---- prologue: stage U (bf16, swizzled) ----
    for (int i = tid; i < 128 * 28; i += NTH) {
        int row = i / 28, c8 = i % 28;
        bf16x8 val = {0,0,0,0,0,0,0,0};
        if (c8 < 25) {
            const float* p = Ub + row * Dd + c8 * 8;
            val = pack8(*(const f32x4*)p, *(const f32x4*)(p + 4));
        }
        unsigned a = OFF_USH + (unsigned)row * 448u + (unsigned)c8 * 16u;
        *(bf16x8*)(smem + (a ^ ((unsigned)(row & 7) << 4))) = val;
    }
    // stage tile 0 (load+write now); keep raw f32 in pv regs for the G[:,0:200] copy
    f32x4 pv0 = {0,0,0,0}, pv1 = {0,0,0,0};
    stage_load(Hb, tid, pv0, pv1);
    stage_write(smem, tid, 0, pv0, pv1, wmA, wmB, whA, whB);
    // su[j] = dot(U_j, wu) + b  (from global, once per block)
    for (int jj = 0; jj < 8; ++jj) {
        int j = wv * 8 + jj;
        const float* up = Ub + j * Dd;
        float v = up[lane] * wu0 + up[64 + lane] * wu1 + up[128 + lane] * wu2;
        if (lane < 8) v += up[192 + lane] * wu3;
        #pragma unroll
        for (int off = 32; off; off >>= 1) v += __shfl_xor(v, off);
        if (lane == 0) *(float*)(smem + OFF_SUS + (unsigned)j * 4u) = v + bb;
    }
    __syncthreads();   // prologue barrier (full drain, once)

    // build Ujt[d][j] = Ush[j][d] (bf16, swizzled), zero rows for d>=200
    for (int i = tid; i < 208 * 64; i += NTH) {
        int d  = i >> 6;
        int jp = (i & 63) << 1;
        unsigned short v0 = 0, v1 = 0;
        if (d < Dd) {
            unsigned a0 = OFF_USH + (unsigned)jp * 448u + ((unsigned)d << 1);
            v0 = *(const unsigned short*)(smem + (a0 ^ ((unsigned)(jp & 7) << 4)));
            unsigned a1 = OFF_USH + (unsigned)(jp + 1) * 448u + ((unsigned)d << 1);
            v1 = *(const unsigned short*)(smem + (a1 ^ ((unsigned)((jp + 1) & 7) << 4)));
        }
        unsigned pk = (unsigned)v0 | ((unsigned)v1 << 16);
        unsigned wa = OFF_UJT + (unsigned)d * 256u + (unsigned)((i & 63) << 2);
        *(unsigned*)(smem + (wa ^ ((unsigned)(d & 7) << 4))) = pk;
    }
    // (Ujt consumed after B1/B2/B3 of tile 0 -> lgkm-barriers order it)

    // wave geometry: 2 row-groups x 8 col-groups
    const int rg  = wv >> 3;                 // 0..1
    const int cg  = wv & 7;                  // 0..7
    const int l15 = lane & 15;
    const int lq  = lane >> 4;               // quarter 0..3
    const unsigned kfo = (unsigned)(lq << 4);
    const int rowA    = rg * 16 + l15;       // A-fragment row
    const int rowBase = rg * 16 + (lq << 2); // C-fragment row base
    const int jcol    = cg * 16 + l15;       // S-phase column (j)
    const int  dt1  = cg + 8;
    const bool has2 = (dt1 < 13);
    const int  dcol0 = cg * 16 + l15;        // 0..127
    const int  dcol1 = dt1 * 16 + l15;       // 128..207 (has2)
    const bool use1  = has2 && (dcol1 < Dd);

    const unsigned hswz = (unsigned)(rowA & 7) << 4;
    const unsigned ubase = OFF_USH + (unsigned)jcol * 448u;
    const unsigned uswz  = (unsigned)(jcol & 7) << 4;
    const unsigned pbase = OFF_PSH + (unsigned)rowA * 256u;
    const unsigned pswz  = (unsigned)(rowA & 7) << 4;

    for (int tile = 0; tile < NT; ++tile) {
        const int cur = tile & 1, nxt = cur ^ 1;
        const float* Ht = Hb + (size_t)tile * TILE * Dd;
        const bool havenext = (tile + 1 < NT);

        // A: issue next-tile loads + this tile's epilogue-H loads (all fire now)
        f32x4 nh0 = {0,0,0,0}, nh1 = {0,0,0,0};
        if (havenext) stage_load(Ht + TILE * Dd, tid, nh0, nh1);
        float eh0[4], eh1[4];
        #pragma unroll
        for (int r = 0; r < 4; ++r) {
            eh0[r] = Ht[(rowBase + r) * Dd + dcol0];
            eh1[r] = use1 ? Ht[(rowBase + r) * Dd + dcol1] : 0.f;
        }

        // B: S MFMA
        f32x4 acc = {0.f, 0.f, 0.f, 0.f};
        const unsigned hbase = OFF_HMS + (unsigned)cur * 14336u + (unsigned)rowA * 448u;
        #pragma unroll
        for (int ki = 0; ki < 7; ++ki) {
            bf16x8 af = *(const bf16x8*)(smem + ((hbase + (unsigned)ki * 64u + kfo) ^ hswz));
            bf16x8 bf = *(const bf16x8*)(smem + ((ubase + (unsigned)ki * 64u + kfo) ^ uswz));
            acc = __builtin_amdgcn_mfma_f32_16x16x32_bf16(af, bf, acc, 0, 0, 0);
        }

        // C: softmax over j
        const float suv = *(const float*)(smem + OFF_SUS + (unsigned)jcol * 4u);
        f32x4 sh4 = *(const f32x4*)(smem + OFF_SHS + (unsigned)cur * 128u + (unsigned)rowBase * 4u);
        float sv[4], ev[4], Mv[4];
        #pragma unroll
        for (int r = 0; r < 4; ++r) {
            float s = acc[r] + sh4[r] + suv;
            sv[r] = s;
            float m = s;
            m = fmaxf(m, __shfl_xor(m, 1));
            m = fmaxf(m, __shfl_xor(m, 2));
            m = fmaxf(m, __shfl_xor(m, 4));
            m = fmaxf(m, __shfl_xor(m, 8));
            if (l15 == 0)
                *(float*)(smem + OFF_SMX + (unsigned)((rowBase + r) * 8 + cg) * 4u) = m;
        }
        bar_lds();   // B1
        #pragma unroll
        for (int r = 0; r < 4; ++r) {
            f32x4 ma  = *(const f32x4*)(smem + OFF_SMX + (unsigned)(rowBase + r) * 32u);
            f32x4 mb2 = *(const f32x4*)(smem + OFF_SMX + (unsigned)(rowBase + r) * 32u + 16u);
            float M = fmaxf(fmaxf(fmaxf(ma[0], ma[1]), fmaxf(ma[2], ma[3])),
                            fmaxf(fmaxf(mb2[0], mb2[1]), fmaxf(mb2[2], mb2[3])));
            Mv[r] = M;
            float e = __expf(sv[r] - M);
            ev[r] = e;
            float ssum = e;
            ssum += __shfl_xor(ssum, 1); ssum += __shfl_xor(ssum, 2);
            ssum += __shfl_xor(ssum, 4); ssum += __shfl_xor(ssum, 8);
            if (l15 == 0)
                *(float*)(smem + OFF_SSM + (unsigned)((rowBase + r) * 8 + cg) * 4u) = ssum;
        }
        if (cg == 0 && l15 == 0) {
            #pragma unroll
            for (int r = 0; r < 4; ++r)
                mrow[(size_t)b * Tt + t0 + tile * TILE + rowBase + r] = Mv[r];
        }
        bar_lds();   // B2
        #pragma unroll
        for (int r = 0; r < 4; ++r) {
            f32x4 sa = *(const f32x4*)(smem + OFF_SSM + (unsigned)(rowBase + r) * 32u);
            f32x4 sb = *(const f32x4*)(smem + OFF_SSM + (unsigned)(rowBase + r) * 32u + 16u);
            float inv = 1.f / (sa[0] + sa[1] + sa[2] + sa[3] + sb[0] + sb[1] + sb[2] + sb[3]);
            float p  = ev[r] * inv;
            float pn = __shfl_down(p, 1);
            if (!(lane & 1)) {
                int row = rowBase + r;
                unsigned a0 = OFF_PSH + (unsigned)row * 256u + (unsigned)jcol * 2u;
                *(unsigned*)(smem + (a0 ^ ((unsigned)(row & 7) << 4))) =
                    (unsigned)f2bf(p) | ((unsigned)f2bf(pn) << 16);
            }
        }
        bar_lds();   // B3: P ready

        // D: PV MFMA
        f32x4 acc0 = {0.f,0.f,0.f,0.f}, acc1 = {0.f,0.f,0.f,0.f};
        #pragma unroll
        for (int ki = 0; ki < 4; ++ki) {
            bf16x8 af = *(const bf16x8*)(smem + ((pbase + (unsigned)ki * 64u + kfo) ^ pswz));
            bf16x8 b0 = *(const bf16x8*)(smem +
                ((OFF_UJT + (unsigned)dcol0 * 256u + (unsigned)ki * 64u + kfo) ^ ((unsigned)(dcol0 & 7) << 4)));
            acc0 = __builtin_amdgcn_mfma_f32_16x16x32_bf16(af, b0, acc0, 0, 0, 0);
            if (has2) {
                bf16x8 b1 = *(const bf16x8*)(smem +
                    ((OFF_UJT + (unsigned)dcol1 * 256u + (unsigned)ki * 64u + kfo) ^ ((unsigned)(dcol1 & 7) << 4)));
                acc1 = __builtin_amdgcn_mfma_f32_16x16x32_bf16(af, b1, acc1, 0, 0, 0);
            }
        }

        // E: epilogue stores (fire-and-forget; never waited in-loop)
        float* Gtile = G + ((size_t)b * Tt + t0 + (size_t)tile * TILE) * GD;
        #pragma unroll
        for (int r = 0; r < 4; ++r) {
            float* grow = Gtile + (size_t)(rowBase + r) * GD;
            grow[200 + dcol0] = acc0[r];
            grow[400 + dcol0] = eh0[r] * acc0[r];
            if (use1) {
                grow[200 + dcol1] = acc1[r];
                grow[400 + dcol1] = eh1[r] * acc1[r];
            }
        }
        {   // H copy from prev-staged regs (no global re-read)
            const int row = tid >> 5;
            if (cc < 25) {
                float* gp = Gtile + (size_t)row * GD + cc * 8;
                *(f32x4*)gp       = pv0;
                *(f32x4*)(gp + 4) = pv1;
            }
        }

        // F: write next tile's staging to LDS (vmcnt wait here is counted, not 0)
        if (havenext) {
            stage_write(smem, tid, nxt, nh0, nh1, wmA, wmB, whA, whB);
            pv0 = nh0; pv1 = nh1;
            bar_lds();   // B4: Hms[nxt]/sh[nxt] ready
        }
    }
}

// ---------------------------------------------------------------------------
// K2: fused q-softmax + H_tilde partials.
//   every block re-derives M,S from mrow[b,:] (8 KB, L2-hot);
//   ch==0 block writes q; all blocks atomicAdd their H_tilde partial.
// ---------------------------------------------------------------------------
__global__ __launch_bounds__(256) void k_htq(
    const float* __restrict__ H, const float* __restrict__ mrow,
    float* __restrict__ q, float* __restrict__ htil)
{
    __shared__ float red[4];
    __shared__ float sM, sS;
    const int b = blockIdx.y, ch = blockIdx.x;
    const int tid = threadIdx.x, lane = tid & 63, wvv = tid >> 6;
    const float* mb = mrow + (size_t)b * Tt;

    float lm = -1e30f;
    for (int i = tid; i < Tt; i += 256) lm = fmaxf(lm, mb[i]);
    #pragma unroll
    for (int off = 32; off; off >>= 1) lm = fmaxf(lm, __shfl_xor(lm, off));
    if (lane == 0) red[wvv] = lm;
    __syncthreads();
    if (tid == 0) sM = fmaxf(fmaxf(red[0], red[1]), fmaxf(red[2], red[3]));
    __syncthreads();
    const float M = sM;

    float ls = 0.f;
    for (int i = tid; i < Tt; i += 256) ls += __expf(mb[i] - M);
    #pragma unroll
    for (int off = 32; off; off >>= 1) ls += __shfl_xor(ls, off);
    __syncthreads();
    if (lane == 0) red[wvv] = ls;
    __syncthreads();
    if (tid == 0) sS = red[0] + red[1] + red[2] + red[3];
    __syncthreads();
    const float invS = 1.f / sS;

    if (ch == 0) {
        for (int i = tid; i < Tt; i += 256)
            q[(size_t)b * Tt + i] = __expf(mb[i] - M) * invS;
    }

    const int d4 = tid & 63;
    const int tp = tid >> 6;
    if (d4 >= 50) return;
    const float* Hb = H + (size_t)b * Tt * Dd;
    f32x4 acc = {0.f, 0.f, 0.f, 0.f};
    const int tbase = ch * 128 + tp * 32;
    for (int k = 0; k < 32; ++k) {
        int t = tbase + k;
        float p = __expf(mb[t] - M);
        f32x4 h4 = *(const f32x4*)(Hb + (size_t)t * Dd + d4 * 4);
        acc += h4 * p;
    }
    acc *= invS;
    float* hp = htil + b * Dd + d4 * 4;
    atomicAdd(hp + 0, acc[0]); atomicAdd(hp + 1, acc[1]);
    atomicAdd(hp + 2, acc[2]); atomicAdd(hp + 3, acc[3]);
}

// ---------------------------------------------------------------------------
// K3: G[:,600:800] = H * htil[b,:]   (f32x4 vectorized)
// ---------------------------------------------------------------------------
__global__ __launch_bounds__(256) void k_g3(
    const float* __restrict__ H, const float* __restrict__ htil,
    float* __restrict__ G)
{
    const int idx = blockIdx.x * 256 + threadIdx.x;   // over Bb*Tt*50 f32x4 chunks
    if (idx >= Bb * Tt * 50) return;
    const int d4 = idx % 50;
    const int bt = idx / 50;
    const int b  = bt >> 11;
    f32x4 h4 = *(const f32x4*)(H + (size_t)bt * Dd + d4 * 4);
    f32x4 t4 = *(const f32x4*)(htil + b * Dd + d4 * 4);
    *(f32x4*)(G + (size_t)bt * GD + 600 + d4 * 4) = h4 * t4;
}

// ---------------------------------------------------------------------------
extern "C" void kernel_launch(void* const* d_in, const int* in_sizes, int n_in,
                              void* d_out, int out_size, void* d_ws, size_t ws_size,
                              hipStream_t stream)
{
    const float* H    = (const float*)d_in[0];
    const float* U    = (const float*)d_in[1];
    const float* wt   = (const float*)d_in[2];
    const float* bptr = (const float*)d_in[3];

    float* G    = (float*)d_out;
    float* q    = G + (size_t)Bb * Tt * GD;     // output 1 region
    float* mrow = (float*)d_ws;                 // B*T floats
    float* htil = mrow + (size_t)Bb * Tt;       // B*Dd floats

    hipMemsetAsync(htil, 0, (size_t)Bb * Dd * sizeof(float), stream);

    k_main<<<(Bb * Tt / ROWS_BLK), NTH, 0, stream>>>(H, U, wt, bptr, G, mrow);

    dim3 g2(Tt / 128, Bb);
    k_htq<<<g2, 256, 0, stream>>>(H, mrow, q, htil);

    const int n3 = Bb * Tt * 50;
    k_g3<<<(n3 + 255) / 256, 256, 0, stream>>>(H, htil, G);
}